// Round 3
// baseline (1533.242 us; speedup 1.0000x reference)
//
#include <hip/hip_runtime.h>
#include <math.h>

// AnyNet stereo forward, fp32. Round 3: COUT-split conv3d for occupancy
// (each block owns a channel-group slice; no reduction needed), depth fused
// into pred0 upsample.

#define FULL_H 512
#define FULL_W 1280
#define NB 8
#define NPIX (NB * FULL_H * FULL_W)   // 5,242,880

// ---------------- stage-0 L1 cost volume ----------------
__global__ __launch_bounds__(256) void cost0_k(const float* __restrict__ fl,
                                               const float* __restrict__ fr,
                                               float* __restrict__ cost) {
    const int H = 32, W = 80, D = 12, C = 8;
    int idx = blockIdx.x * 256 + threadIdx.x;
    int total = NB * D * H * W;
    if (idx >= total) return;
    int w = idx % W; int t = idx / W;
    int h = t % H; t /= H;
    int d = t % D; int b = t / D;
    int src = w - d;
    float acc = 0.f;
    for (int c = 0; c < C; ++c) {
        int base = ((b * C + c) * H + h) * W;
        float flv = fl[base + w];
        float frv = (src >= 0) ? fr[base + src] : 0.f;
        acc += fabsf(flv - frv);
    }
    cost[((b * D + d) * H + h) * W + w] = acc;
}

// ---------------- residual (warped) cost volume, S=5 shifts -2..2 ----------------
__global__ __launch_bounds__(256) void costres_k(const float* __restrict__ fl,
                                                 const float* __restrict__ fr,
                                                 const float* __restrict__ wf,
                                                 float* __restrict__ cost,
                                                 int H, int W) {
    const int C = 8, S = 5;
    int idx = blockIdx.x * 256 + threadIdx.x;
    int total = NB * S * H * W;
    if (idx >= total) return;
    int w = idx % W; int t = idx / W;
    int h = t % H; t /= H;
    int s = t % S; int b = t / S;
    float disp  = wf[(b * H + h) * W + w];
    float shift = (float)(s - 2);
    float xs  = (float)w - (disp - shift);
    float x0f = floorf(xs);
    float w1  = xs - x0f;
    float x0fc = fminf(fmaxf(x0f, -2.f), (float)W);
    int x0 = (int)x0fc;
    int x1 = x0 + 1;
    float m0 = (x0 >= 0 && x0 <= W - 1) ? (1.f - w1) : 0.f;
    float m1 = (x1 >= 0 && x1 <= W - 1) ? w1 : 0.f;
    int x0c = min(max(x0, 0), W - 1);
    int x1c = min(max(x1, 0), W - 1);
    float acc = 0.f;
    const float* flb = fl + ((b * C) * H + h) * W;
    const float* frb = fr + ((b * C) * H + h) * W;
    for (int c = 0; c < C; ++c) {
        float v = frb[x0c] * m0 + frb[x1c] * m1;
        acc += fabsf(flb[w] - v);
        flb += H * W;
        frb += H * W;
    }
    cost[idx] = acc;
}

// ---------------- COUT-split register-blocked 3x3x3 SAME conv3d ----------------
// x: [B,CIN,D,H,W]  wg: [COUTT,CIN,27]  y: [B,COUTT,D,H,W]
// Grid = nsb * (COUTT/COUTS); each block handles channel group cog of COUTS
// channels for a chunk of w-strips (WT consecutive w outputs per thread).
// Requires W % WT == 0 and WT % 4 == 0.
template <int CIN, int COUTT, int COUTS, int WT, bool RELU>
__global__ __launch_bounds__(256) void conv3_k(const float* __restrict__ x,
                                               const float* __restrict__ wg,
                                               float* __restrict__ y,
                                               int D, int H, int W, int nstrips) {
    constexpr int NSPL = COUTT / COUTS;
    int cog, sb;
    if constexpr (NSPL > 1) { cog = blockIdx.x % NSPL; sb = blockIdx.x / NSPL; }
    else { cog = 0; sb = blockIdx.x; }

    __shared__ __align__(16) float wl[CIN * 27 * COUTS];
    for (int i = threadIdx.x; i < CIN * 27 * COUTS; i += 256) {
        int co = i % COUTS; int rest = i / COUTS;
        int tap = rest % 27; int ci = rest / 27;
        wl[i] = wg[((cog * COUTS + co) * CIN + ci) * 27 + tap];
    }
    __syncthreads();

    int idx = sb * 256 + threadIdx.x;
    if (idx >= nstrips) return;
    const int SW = W / WT;
    int sw = idx % SW; int t = idx / SW;
    int h = t % H; t /= H;
    int d = t % D; int b = t / D;
    const int wbase = sw * WT;
    const int chs = D * H * W;

    float acc[COUTS][WT];
#pragma unroll
    for (int co = 0; co < COUTS; ++co)
#pragma unroll
        for (int wt = 0; wt < WT; ++wt) acc[co][wt] = 0.f;

    const bool has_lo = (wbase > 0);
    const bool has_hi = (wbase + WT < W);
    const float* xb = x + (size_t)b * CIN * chs;

    for (int ci = 0; ci < CIN; ++ci) {
        const float* xc = xb + ci * chs;
#pragma unroll
        for (int kd = 0; kd < 3; ++kd) {
            int dd = d + kd - 1; if (dd < 0 || dd >= D) continue;
#pragma unroll
            for (int kh = 0; kh < 3; ++kh) {
                int hh = h + kh - 1; if (hh < 0 || hh >= H) continue;
                const float* row = xc + (dd * H + hh) * W + wbase;
                float xr[WT + 2];
#pragma unroll
                for (int j = 0; j < WT / 4; ++j) {
                    float4 v = *reinterpret_cast<const float4*>(row + j * 4);
                    xr[1 + j * 4 + 0] = v.x; xr[1 + j * 4 + 1] = v.y;
                    xr[1 + j * 4 + 2] = v.z; xr[1 + j * 4 + 3] = v.w;
                }
                xr[0]      = has_lo ? row[-1] : 0.f;
                xr[WT + 1] = has_hi ? row[WT] : 0.f;
                const int tapbase = ci * 27 + kd * 9 + kh * 3;
#pragma unroll
                for (int kw = 0; kw < 3; ++kw) {
                    const float* wp = &wl[(tapbase + kw) * COUTS];
                    if constexpr (COUTS == 1) {
                        float wv = wp[0];
#pragma unroll
                        for (int wt = 0; wt < WT; ++wt)
                            acc[0][wt] = fmaf(xr[wt + kw], wv, acc[0][wt]);
                    } else if constexpr (COUTS == 2) {
                        float2 w2 = *reinterpret_cast<const float2*>(wp);
#pragma unroll
                        for (int wt = 0; wt < WT; ++wt) {
                            float xv = xr[wt + kw];
                            acc[0][wt] = fmaf(xv, w2.x, acc[0][wt]);
                            acc[1][wt] = fmaf(xv, w2.y, acc[1][wt]);
                        }
                    } else {
                        float4 w4[COUTS / 4];
#pragma unroll
                        for (int q = 0; q < COUTS / 4; ++q)
                            w4[q] = reinterpret_cast<const float4*>(wp)[q];
#pragma unroll
                        for (int wt = 0; wt < WT; ++wt) {
                            float xv = xr[wt + kw];
#pragma unroll
                            for (int q = 0; q < COUTS / 4; ++q) {
                                acc[q * 4 + 0][wt] = fmaf(xv, w4[q].x, acc[q * 4 + 0][wt]);
                                acc[q * 4 + 1][wt] = fmaf(xv, w4[q].y, acc[q * 4 + 1][wt]);
                                acc[q * 4 + 2][wt] = fmaf(xv, w4[q].z, acc[q * 4 + 2][wt]);
                                acc[q * 4 + 3][wt] = fmaf(xv, w4[q].w, acc[q * 4 + 3][wt]);
                            }
                        }
                    }
                }
            }
        }
    }

    float* yb = y + (size_t)b * COUTT * chs + (size_t)cog * COUTS * chs + (d * H + h) * W + wbase;
#pragma unroll
    for (int co = 0; co < COUTS; ++co) {
#pragma unroll
        for (int j = 0; j < WT / 4; ++j) {
            float4 v;
            v.x = acc[co][j * 4 + 0]; v.y = acc[co][j * 4 + 1];
            v.z = acc[co][j * 4 + 2]; v.w = acc[co][j * 4 + 3];
            if (RELU) {
                v.x = fmaxf(v.x, 0.f); v.y = fmaxf(v.y, 0.f);
                v.z = fmaxf(v.z, 0.f); v.w = fmaxf(v.w, 0.f);
            }
            *reinterpret_cast<float4*>(yb + co * chs + j * 4) = v;
        }
    }
}

// ---------------- softargmin disparity regression ----------------
__global__ __launch_bounds__(256) void dispreg_k(const float* __restrict__ cost,
                                                 float* __restrict__ dsm,
                                                 int total, int D, int HW,
                                                 float dstart, float scale) {
    int idx = blockIdx.x * 256 + threadIdx.x;
    if (idx >= total) return;
    int hw = idx % HW; int b = idx / HW;
    const float* c = cost + b * D * HW + hw;
    float m = -1e30f;
    for (int d = 0; d < D; ++d) m = fmaxf(m, -c[d * HW]);
    float s = 0.f, ws = 0.f;
    for (int d = 0; d < D; ++d) {
        float e = expf(-c[d * HW] - m);
        s += e;
        ws = fmaf(e, dstart + (float)d, ws);
    }
    dsm[idx] = ws / s * scale;
}

// ---------------- bilinear upsample + optional residual + optional depth ----------------
__global__ __launch_bounds__(256) void upsample_add_k(const float* __restrict__ s,
                                                      int sh, int sw,
                                                      const float* __restrict__ prev,
                                                      float* __restrict__ out,
                                                      float* __restrict__ dep) {
    int idx = blockIdx.x * 256 + threadIdx.x;
    if (idx >= NPIX) return;
    int x = idx % FULL_W; int t = idx / FULL_W;
    int y = t % FULL_H; int b = t / FULL_H;
    float fy = (y + 0.5f) * ((float)sh / FULL_H) - 0.5f;
    float fx = (x + 0.5f) * ((float)sw / FULL_W) - 0.5f;
    int y0 = (int)floorf(fy); float wy = fy - (float)y0;
    int x0 = (int)floorf(fx); float wx = fx - (float)x0;
    int y0c = min(max(y0, 0), sh - 1), y1c = min(max(y0 + 1, 0), sh - 1);
    int x0c = min(max(x0, 0), sw - 1), x1c = min(max(x0 + 1, 0), sw - 1);
    const float* sb = s + b * sh * sw;
    float v00 = sb[y0c * sw + x0c], v01 = sb[y0c * sw + x1c];
    float v10 = sb[y1c * sw + x0c], v11 = sb[y1c * sw + x1c];
    float v = (1.f - wy) * ((1.f - wx) * v00 + wx * v01) +
              wy        * ((1.f - wx) * v10 + wx * v11);
    if (prev) v += prev[idx];
    out[idx] = v;
    if (dep) {
        float p = fabsf(v);
        float d = 64.f / p;                 // BASELINE*FOCAL
        if (isnan(d)) d = 100.f;
        d = fminf(fmaxf(d, 0.1f), 100.f);
        dep[idx] = d;
    }
}

// ---------------- antialiased triangle downsample + scale ----------------
__global__ __launch_bounds__(256) void wflow_k(const float* __restrict__ pred,
                                               float* __restrict__ wf,
                                               int oh, int ow, int f, float scale) {
    int idx = blockIdx.x * 256 + threadIdx.x;
    int total = NB * oh * ow;
    if (idx >= total) return;
    int ox = idx % ow; int t = idx / ow;
    int oy = t % oh; int b = t / oh;
    float ff = (float)f, invf = 1.f / (float)f;
    float cy = (oy + 0.5f) * ff - 0.5f;
    float cx = (ox + 0.5f) * ff - 0.5f;
    int ylo = max((int)ceilf(cy - ff), 0);
    int yhi = min((int)floorf(cy + ff), FULL_H - 1);
    int xlo = max((int)ceilf(cx - ff), 0);
    int xhi = min((int)floorf(cx + ff), FULL_W - 1);
    const float* pb = pred + b * FULL_H * FULL_W;
    float acc = 0.f, wys = 0.f, wxs = 0.f;
    for (int iy = ylo; iy <= yhi; ++iy) {
        float wy = 1.f - fabsf((float)iy - cy) * invf;
        wys += wy;
        float rowacc = 0.f;
        const float* row = pb + iy * FULL_W;
        for (int ix = xlo; ix <= xhi; ++ix) {
            float wx = 1.f - fabsf((float)ix - cx) * invf;
            rowacc = fmaf(wx, row[ix], rowacc);
        }
        acc = fmaf(wy, rowacc, acc);
    }
    for (int ix = xlo; ix <= xhi; ++ix) wxs += 1.f - fabsf((float)ix - cx) * invf;
    wf[idx] = acc / (wys * wxs) * scale;
}

static inline dim3 g(int n) { return dim3((n + 255) / 256); }
static inline dim3 gs(int nstrips, int nspl) { return dim3(((nstrips + 255) / 256) * nspl); }

extern "C" void kernel_launch(void* const* d_in, const int* in_sizes, int n_in,
                              void* d_out, int out_size, void* d_ws, size_t ws_size,
                              hipStream_t stream) {
    const float* f_l0  = (const float*)d_in[0];
    const float* f_r0  = (const float*)d_in[1];
    const float* f_l1  = (const float*)d_in[2];
    const float* f_r1  = (const float*)d_in[3];
    const float* f_l2  = (const float*)d_in[4];
    const float* f_r2  = (const float*)d_in[5];
    const float* w_in0  = (const float*)d_in[6];
    const float* w_mid0 = (const float*)d_in[7];
    const float* w_out0 = (const float*)d_in[8];
    const float* w_in1  = (const float*)d_in[9];
    const float* w_mid1 = (const float*)d_in[10];
    const float* w_out1 = (const float*)d_in[11];
    const float* w_in2  = (const float*)d_in[12];
    const float* w_mid2 = (const float*)d_in[13];
    const float* w_out2 = (const float*)d_in[14];

    float* out   = (float*)d_out;
    float* pred0 = out;
    float* pred1 = out + NPIX;
    float* pred2 = out + 2 * NPIX;
    float* depth = out + 3 * NPIX;

    float* ws   = (float*)d_ws;
    float* xA   = ws;                 // 6,553,600 floats
    float* xB   = xA + 6553600;       // 6,553,600
    float* cost = xB + 6553600;       // 1,638,400
    float* dsm  = cost + 1638400;     // 327,680
    float* wfl  = dsm + 327680;       // 327,680

    dim3 blk(256);

    // ---------------- stage 0 ----------------
    {
        const int D = 12, H = 32, W = 80;
        const int total = NB * D * H * W;          // 245,760
        cost0_k<<<g(total), blk, 0, stream>>>(f_l0, f_r0, cost);
        int ns4 = total / 4;                       // 61,440 strips (WT=4)
        conv3_k<1, 16, 4, 4, true><<<gs(ns4, 4), blk, 0, stream>>>(cost, w_in0, xA, D, H, W, ns4);
        const float* src = xA; float* dst = xB;
        for (int k = 0; k < 4; ++k) {
            conv3_k<16, 16, 2, 4, true><<<gs(ns4, 8), blk, 0, stream>>>(src, w_mid0 + k * 16 * 16 * 27, dst, D, H, W, ns4);
            const float* nsrc = dst; dst = (float*)src; src = nsrc;
        }
        conv3_k<16, 1, 1, 4, false><<<gs(ns4, 1), blk, 0, stream>>>(src, w_out0, cost, D, H, W, ns4);
        dispreg_k<<<g(NB * H * W), blk, 0, stream>>>(cost, dsm, NB * H * W, D, H * W, 0.f, 16.f);
        upsample_add_k<<<g(NPIX), blk, 0, stream>>>(dsm, H, W, nullptr, pred0, depth);
    }

    // ---------------- stage 1 ----------------
    {
        const int D = 5, H = 64, W = 160;
        const int total = NB * D * H * W;          // 409,600
        wflow_k<<<g(NB * H * W), blk, 0, stream>>>(pred0, wfl, H, W, 8, 0.125f);
        costres_k<<<g(total), blk, 0, stream>>>(f_l1, f_r1, wfl, cost, H, W);
        int ns4 = total / 4;                       // 102,400
        conv3_k<1, 4, 2, 4, true><<<gs(ns4, 2), blk, 0, stream>>>(cost, w_in1, xA, D, H, W, ns4);
        const float* src = xA; float* dst = xB;
        for (int k = 0; k < 4; ++k) {
            conv3_k<4, 4, 2, 4, true><<<gs(ns4, 2), blk, 0, stream>>>(src, w_mid1 + k * 4 * 4 * 27, dst, D, H, W, ns4);
            const float* nsrc = dst; dst = (float*)src; src = nsrc;
        }
        conv3_k<4, 1, 1, 4, false><<<gs(ns4, 1), blk, 0, stream>>>(src, w_out1, cost, D, H, W, ns4);
        dispreg_k<<<g(NB * H * W), blk, 0, stream>>>(cost, dsm, NB * H * W, D, H * W, -2.f, 8.f);
        upsample_add_k<<<g(NPIX), blk, 0, stream>>>(dsm, H, W, pred0, pred1, nullptr);
    }

    // ---------------- stage 2 ----------------
    {
        const int D = 5, H = 128, W = 320;
        const int total = NB * D * H * W;          // 1,638,400
        wflow_k<<<g(NB * H * W), blk, 0, stream>>>(pred1, wfl, H, W, 4, 0.25f);
        costres_k<<<g(total), blk, 0, stream>>>(f_l2, f_r2, wfl, cost, H, W);
        int ns8 = total / 8;                       // 204,800
        conv3_k<1, 4, 2, 8, true><<<gs(ns8, 2), blk, 0, stream>>>(cost, w_in2, xA, D, H, W, ns8);
        const float* src = xA; float* dst = xB;
        for (int k = 0; k < 4; ++k) {
            conv3_k<4, 4, 2, 8, true><<<gs(ns8, 2), blk, 0, stream>>>(src, w_mid2 + k * 4 * 4 * 27, dst, D, H, W, ns8);
            const float* nsrc = dst; dst = (float*)src; src = nsrc;
        }
        conv3_k<4, 1, 1, 8, false><<<gs(ns8, 1), blk, 0, stream>>>(src, w_out2, cost, D, H, W, ns8);
        dispreg_k<<<g(NB * H * W), blk, 0, stream>>>(cost, dsm, NB * H * W, D, H * W, -2.f, 4.f);
        upsample_add_k<<<g(NPIX), blk, 0, stream>>>(dsm, H, W, pred1, pred2, nullptr);
    }
}

// Round 4
// 1062.755 us; speedup vs baseline: 1.4427x; 1.4427x over previous
//
#include <hip/hip_runtime.h>
#include <math.h>

// AnyNet stereo forward, fp32. Round 4: zero-padded activations ->
// branch-free conv inner loops (software-pipelineable loads); no COUT split
// (R3 regression reverted). Padded layout: [B][C][D+2][H+2][W+8], interior
// at (d+1, h+1, w+4), halos zeroed via hipMemsetAsync per stage.

#define FULL_H 512
#define FULL_W 1280
#define NB 8
#define NPIX (NB * FULL_H * FULL_W)   // 5,242,880

// ---------------- stage-0 L1 cost volume -> padded ----------------
__global__ __launch_bounds__(256) void cost0p_k(const float* __restrict__ fl,
                                                const float* __restrict__ fr,
                                                float* __restrict__ costp) {
    const int H = 32, W = 80, D = 12, C = 8;
    const int DZ = 14, HZ = 34, WZ = 88;
    int idx = blockIdx.x * 256 + threadIdx.x;
    int total = NB * D * H * W;
    if (idx >= total) return;
    int w = idx % W; int t = idx / W;
    int h = t % H; t /= H;
    int d = t % D; int b = t / D;
    int src = w - d;
    float acc = 0.f;
    for (int c = 0; c < C; ++c) {
        int base = ((b * C + c) * H + h) * W;
        float flv = fl[base + w];
        float frv = (src >= 0) ? fr[base + src] : 0.f;
        acc += fabsf(flv - frv);
    }
    costp[((b * DZ + (d + 1)) * HZ + (h + 1)) * WZ + (w + 4)] = acc;
}

// ---------------- residual (warped) cost volume -> padded ----------------
__global__ __launch_bounds__(256) void costresp_k(const float* __restrict__ fl,
                                                  const float* __restrict__ fr,
                                                  const float* __restrict__ wf,
                                                  float* __restrict__ costp,
                                                  int H, int W, int HZ, int WZ) {
    const int C = 8, S = 5, DZ = 7;
    int idx = blockIdx.x * 256 + threadIdx.x;
    int total = NB * S * H * W;
    if (idx >= total) return;
    int w = idx % W; int t = idx / W;
    int h = t % H; t /= H;
    int s = t % S; int b = t / S;
    float disp  = wf[(b * H + h) * W + w];
    float shift = (float)(s - 2);
    float xs  = (float)w - (disp - shift);
    float x0f = floorf(xs);
    float w1  = xs - x0f;
    float x0fc = fminf(fmaxf(x0f, -2.f), (float)W);
    int x0 = (int)x0fc;
    int x1 = x0 + 1;
    float m0 = (x0 >= 0 && x0 <= W - 1) ? (1.f - w1) : 0.f;
    float m1 = (x1 >= 0 && x1 <= W - 1) ? w1 : 0.f;
    int x0c = min(max(x0, 0), W - 1);
    int x1c = min(max(x1, 0), W - 1);
    float acc = 0.f;
    const float* flb = fl + ((b * C) * H + h) * W;
    const float* frb = fr + ((b * C) * H + h) * W;
    for (int c = 0; c < C; ++c) {
        float v = frb[x0c] * m0 + frb[x1c] * m1;
        acc += fabsf(flb[w] - v);
        flb += H * W;
        frb += H * W;
    }
    costp[((b * DZ + (s + 1)) * HZ + (h + 1)) * WZ + (w + 4)] = acc;
}

// ---------------- padded branch-free 3x3x3 SAME conv3d ----------------
// x: padded [B,CIN,DZ,HZ,WZ]; wg: [COUT,CIN,27];
// y: padded [B,COUT,DZ,HZ,WZ] (PADOUT) or unpadded [B,COUT,D,H,W].
// Each thread: WT consecutive w outputs, all COUT channels. W%WT==0, WT%4==0.
template <int CIN, int COUT, int WT, bool RELU, bool PADOUT>
__global__ __launch_bounds__(256) void convp_k(const float* __restrict__ x,
                                               const float* __restrict__ wg,
                                               float* __restrict__ y,
                                               int D, int H, int W,
                                               int DZ, int HZ, int WZ,
                                               int nstrips) {
    __shared__ __align__(16) float wl[CIN * 27 * COUT];
    for (int i = threadIdx.x; i < CIN * 27 * COUT; i += 256) {
        int co = i % COUT; int rest = i / COUT;
        int tap = rest % 27; int ci = rest / 27;
        wl[i] = wg[(co * CIN + ci) * 27 + tap];
    }
    __syncthreads();

    int idx = blockIdx.x * 256 + threadIdx.x;
    if (idx >= nstrips) return;
    const int SW = W / WT;
    int sw = idx % SW; int t = idx / SW;
    int h = t % H; t /= H;
    int d = t % D; int b = t / D;
    const int wcol = sw * WT + 4;            // padded column of first output
    const int zhs = HZ * WZ;
    const int zcs = DZ * zhs;

    float acc[COUT][WT];
#pragma unroll
    for (int co = 0; co < COUT; ++co)
#pragma unroll
        for (int wt = 0; wt < WT; ++wt) acc[co][wt] = 0.f;

    // interior voxel (d,h) has padded coords (d+1,h+1); tap (kd,kh) in 0..2
    // reads padded (d+kd, h+kh) -- always in bounds, halos are zero.
    const float* xb = x + (size_t)b * CIN * zcs + (size_t)d * zhs + (size_t)h * WZ + wcol;

    for (int ci = 0; ci < CIN; ++ci) {
        const float* xc = xb + (size_t)ci * zcs;
#pragma unroll
        for (int kd = 0; kd < 3; ++kd) {
#pragma unroll
            for (int kh = 0; kh < 3; ++kh) {
                const float* row = xc + kd * zhs + kh * WZ;
                float xr[WT + 2];
#pragma unroll
                for (int j = 0; j < WT / 4; ++j) {
                    float4 v = *reinterpret_cast<const float4*>(row + j * 4);
                    xr[1 + j * 4 + 0] = v.x; xr[1 + j * 4 + 1] = v.y;
                    xr[1 + j * 4 + 2] = v.z; xr[1 + j * 4 + 3] = v.w;
                }
                xr[0]      = row[-1];
                xr[WT + 1] = row[WT];
                const int tapbase = ci * 27 + kd * 9 + kh * 3;
#pragma unroll
                for (int kw = 0; kw < 3; ++kw) {
                    const float* wp = &wl[(tapbase + kw) * COUT];
                    if constexpr (COUT == 1) {
                        float wv = wp[0];
#pragma unroll
                        for (int wt = 0; wt < WT; ++wt)
                            acc[0][wt] = fmaf(xr[wt + kw], wv, acc[0][wt]);
                    } else {
                        float4 w4[COUT / 4];
#pragma unroll
                        for (int q = 0; q < COUT / 4; ++q)
                            w4[q] = reinterpret_cast<const float4*>(wp)[q];
#pragma unroll
                        for (int wt = 0; wt < WT; ++wt) {
                            float xv = xr[wt + kw];
#pragma unroll
                            for (int q = 0; q < COUT / 4; ++q) {
                                acc[q * 4 + 0][wt] = fmaf(xv, w4[q].x, acc[q * 4 + 0][wt]);
                                acc[q * 4 + 1][wt] = fmaf(xv, w4[q].y, acc[q * 4 + 1][wt]);
                                acc[q * 4 + 2][wt] = fmaf(xv, w4[q].z, acc[q * 4 + 2][wt]);
                                acc[q * 4 + 3][wt] = fmaf(xv, w4[q].w, acc[q * 4 + 3][wt]);
                            }
                        }
                    }
                }
            }
        }
    }

    if constexpr (PADOUT) {
        float* yb = y + (size_t)b * COUT * zcs + (size_t)(d + 1) * zhs + (size_t)(h + 1) * WZ + wcol;
#pragma unroll
        for (int co = 0; co < COUT; ++co) {
#pragma unroll
            for (int j = 0; j < WT / 4; ++j) {
                float4 v;
                v.x = acc[co][j * 4 + 0]; v.y = acc[co][j * 4 + 1];
                v.z = acc[co][j * 4 + 2]; v.w = acc[co][j * 4 + 3];
                if (RELU) {
                    v.x = fmaxf(v.x, 0.f); v.y = fmaxf(v.y, 0.f);
                    v.z = fmaxf(v.z, 0.f); v.w = fmaxf(v.w, 0.f);
                }
                *reinterpret_cast<float4*>(yb + (size_t)co * zcs + j * 4) = v;
            }
        }
    } else {
        const int chs = D * H * W;
        float* yb = y + (size_t)b * COUT * chs + (d * H + h) * W + sw * WT;
#pragma unroll
        for (int co = 0; co < COUT; ++co) {
#pragma unroll
            for (int j = 0; j < WT / 4; ++j) {
                float4 v;
                v.x = acc[co][j * 4 + 0]; v.y = acc[co][j * 4 + 1];
                v.z = acc[co][j * 4 + 2]; v.w = acc[co][j * 4 + 3];
                if (RELU) {
                    v.x = fmaxf(v.x, 0.f); v.y = fmaxf(v.y, 0.f);
                    v.z = fmaxf(v.z, 0.f); v.w = fmaxf(v.w, 0.f);
                }
                *reinterpret_cast<float4*>(yb + (size_t)co * chs + j * 4) = v;
            }
        }
    }
}

// ---------------- softargmin disparity regression ----------------
__global__ __launch_bounds__(256) void dispreg_k(const float* __restrict__ cost,
                                                 float* __restrict__ dsm,
                                                 int total, int D, int HW,
                                                 float dstart, float scale) {
    int idx = blockIdx.x * 256 + threadIdx.x;
    if (idx >= total) return;
    int hw = idx % HW; int b = idx / HW;
    const float* c = cost + b * D * HW + hw;
    float m = -1e30f;
    for (int d = 0; d < D; ++d) m = fmaxf(m, -c[d * HW]);
    float s = 0.f, ws = 0.f;
    for (int d = 0; d < D; ++d) {
        float e = expf(-c[d * HW] - m);
        s += e;
        ws = fmaf(e, dstart + (float)d, ws);
    }
    dsm[idx] = ws / s * scale;
}

// ---------------- bilinear upsample + optional residual + optional depth ----------------
__global__ __launch_bounds__(256) void upsample_add_k(const float* __restrict__ s,
                                                      int sh, int sw,
                                                      const float* __restrict__ prev,
                                                      float* __restrict__ out,
                                                      float* __restrict__ dep) {
    int idx = blockIdx.x * 256 + threadIdx.x;
    if (idx >= NPIX) return;
    int x = idx % FULL_W; int t = idx / FULL_W;
    int y = t % FULL_H; int b = t / FULL_H;
    float fy = (y + 0.5f) * ((float)sh / FULL_H) - 0.5f;
    float fx = (x + 0.5f) * ((float)sw / FULL_W) - 0.5f;
    int y0 = (int)floorf(fy); float wy = fy - (float)y0;
    int x0 = (int)floorf(fx); float wx = fx - (float)x0;
    int y0c = min(max(y0, 0), sh - 1), y1c = min(max(y0 + 1, 0), sh - 1);
    int x0c = min(max(x0, 0), sw - 1), x1c = min(max(x0 + 1, 0), sw - 1);
    const float* sb = s + b * sh * sw;
    float v00 = sb[y0c * sw + x0c], v01 = sb[y0c * sw + x1c];
    float v10 = sb[y1c * sw + x0c], v11 = sb[y1c * sw + x1c];
    float v = (1.f - wy) * ((1.f - wx) * v00 + wx * v01) +
              wy        * ((1.f - wx) * v10 + wx * v11);
    if (prev) v += prev[idx];
    out[idx] = v;
    if (dep) {
        float p = fabsf(v);
        float d = 64.f / p;                 // BASELINE*FOCAL
        if (isnan(d)) d = 100.f;
        d = fminf(fmaxf(d, 0.1f), 100.f);
        dep[idx] = d;
    }
}

// ---------------- antialiased triangle downsample + scale ----------------
__global__ __launch_bounds__(256) void wflow_k(const float* __restrict__ pred,
                                               float* __restrict__ wf,
                                               int oh, int ow, int f, float scale) {
    int idx = blockIdx.x * 256 + threadIdx.x;
    int total = NB * oh * ow;
    if (idx >= total) return;
    int ox = idx % ow; int t = idx / ow;
    int oy = t % oh; int b = t / oh;
    float ff = (float)f, invf = 1.f / (float)f;
    float cy = (oy + 0.5f) * ff - 0.5f;
    float cx = (ox + 0.5f) * ff - 0.5f;
    int ylo = max((int)ceilf(cy - ff), 0);
    int yhi = min((int)floorf(cy + ff), FULL_H - 1);
    int xlo = max((int)ceilf(cx - ff), 0);
    int xhi = min((int)floorf(cx + ff), FULL_W - 1);
    const float* pb = pred + b * FULL_H * FULL_W;
    float acc = 0.f, wys = 0.f, wxs = 0.f;
    for (int iy = ylo; iy <= yhi; ++iy) {
        float wy = 1.f - fabsf((float)iy - cy) * invf;
        wys += wy;
        float rowacc = 0.f;
        const float* row = pb + iy * FULL_W;
        for (int ix = xlo; ix <= xhi; ++ix) {
            float wx = 1.f - fabsf((float)ix - cx) * invf;
            rowacc = fmaf(wx, row[ix], rowacc);
        }
        acc = fmaf(wy, rowacc, acc);
    }
    for (int ix = xlo; ix <= xhi; ++ix) wxs += 1.f - fabsf((float)ix - cx) * invf;
    wf[idx] = acc / (wys * wxs) * scale;
}

static inline dim3 g(int n) { return dim3((n + 255) / 256); }

extern "C" void kernel_launch(void* const* d_in, const int* in_sizes, int n_in,
                              void* d_out, int out_size, void* d_ws, size_t ws_size,
                              hipStream_t stream) {
    const float* f_l0  = (const float*)d_in[0];
    const float* f_r0  = (const float*)d_in[1];
    const float* f_l1  = (const float*)d_in[2];
    const float* f_r1  = (const float*)d_in[3];
    const float* f_l2  = (const float*)d_in[4];
    const float* f_r2  = (const float*)d_in[5];
    const float* w_in0  = (const float*)d_in[6];
    const float* w_mid0 = (const float*)d_in[7];
    const float* w_out0 = (const float*)d_in[8];
    const float* w_in1  = (const float*)d_in[9];
    const float* w_mid1 = (const float*)d_in[10];
    const float* w_out1 = (const float*)d_in[11];
    const float* w_in2  = (const float*)d_in[12];
    const float* w_mid2 = (const float*)d_in[13];
    const float* w_out2 = (const float*)d_in[14];

    float* out   = (float*)d_out;
    float* pred0 = out;
    float* pred1 = out + NPIX;
    float* pred2 = out + 2 * NPIX;
    float* depth = out + 3 * NPIX;

    // Workspace (floats), 16B-aligned regions, reused across stages:
    //  P, Q: padded ping-pong activation buffers (max over stages = stage2:
    //        8*4*7*130*328 = 9,551,360). stage0 uses 8*16*14*34*88 = 5,361,664.
    //  CP:   padded cost-volume conv input (max = stage2: 8*7*130*328 = 2,387,840)
    //  CO:   unpadded conv output cost (max = 8*5*128*320 = 1,638,400)
    float* ws = (float*)d_ws;
    float* P    = ws;
    float* Q    = ws + 9551360;
    float* CP   = ws + 19102720;
    float* CO   = ws + 21490560;
    float* dsm  = ws + 23128960;   // 327,680
    float* wfl  = ws + 23456640;   // 327,680  (end: 23,784,320 floats = 95.1 MB)

    dim3 blk(256);

    // ---------------- stage 0 ----------------
    {
        const int D = 12, H = 32, W = 80, DZ = 14, HZ = 34, WZ = 88;
        const size_t pcn = (size_t)NB * 16 * DZ * HZ * WZ;   // 5,361,664
        const size_t cpn = (size_t)NB * DZ * HZ * WZ;        //   335,104
        hipMemsetAsync(P,  0, pcn * 4, stream);
        hipMemsetAsync(Q,  0, pcn * 4, stream);
        hipMemsetAsync(CP, 0, cpn * 4, stream);
        const int total = NB * D * H * W;                    // 245,760
        cost0p_k<<<g(total), blk, 0, stream>>>(f_l0, f_r0, CP);
        int ns4 = total / 4;                                 // 61,440
        int ns8 = total / 8;                                 // 30,720
        convp_k<1, 16, 4, true, true><<<g(ns4), blk, 0, stream>>>(CP, w_in0, P, D, H, W, DZ, HZ, WZ, ns4);
        const float* src = P; float* dst = Q;
        for (int k = 0; k < 4; ++k) {
            convp_k<16, 16, 4, true, true><<<g(ns4), blk, 0, stream>>>(src, w_mid0 + k * 16 * 16 * 27, dst, D, H, W, DZ, HZ, WZ, ns4);
            const float* nsrc = dst; dst = (float*)src; src = nsrc;
        }
        convp_k<16, 1, 8, false, false><<<g(ns8), blk, 0, stream>>>(src, w_out0, CO, D, H, W, DZ, HZ, WZ, ns8);
        dispreg_k<<<g(NB * H * W), blk, 0, stream>>>(CO, dsm, NB * H * W, D, H * W, 0.f, 16.f);
        upsample_add_k<<<g(NPIX), blk, 0, stream>>>(dsm, H, W, nullptr, pred0, depth);
    }

    // ---------------- stage 1 ----------------
    {
        const int D = 5, H = 64, W = 160, DZ = 7, HZ = 66, WZ = 168;
        const size_t pcn = (size_t)NB * 4 * DZ * HZ * WZ;    // 2,483,712
        const size_t cpn = (size_t)NB * DZ * HZ * WZ;        //   620,928
        hipMemsetAsync(P,  0, pcn * 4, stream);
        hipMemsetAsync(Q,  0, pcn * 4, stream);
        hipMemsetAsync(CP, 0, cpn * 4, stream);
        const int total = NB * D * H * W;                    // 409,600
        wflow_k<<<g(NB * H * W), blk, 0, stream>>>(pred0, wfl, H, W, 8, 0.125f);
        costresp_k<<<g(total), blk, 0, stream>>>(f_l1, f_r1, wfl, CP, H, W, HZ, WZ);
        int ns4 = total / 4;                                 // 102,400
        int ns8 = total / 8;                                 //  51,200
        convp_k<1, 4, 4, true, true><<<g(ns4), blk, 0, stream>>>(CP, w_in1, P, D, H, W, DZ, HZ, WZ, ns4);
        const float* src = P; float* dst = Q;
        for (int k = 0; k < 4; ++k) {
            convp_k<4, 4, 4, true, true><<<g(ns4), blk, 0, stream>>>(src, w_mid1 + k * 4 * 4 * 27, dst, D, H, W, DZ, HZ, WZ, ns4);
            const float* nsrc = dst; dst = (float*)src; src = nsrc;
        }
        convp_k<4, 1, 8, false, false><<<g(ns8), blk, 0, stream>>>(src, w_out1, CO, D, H, W, DZ, HZ, WZ, ns8);
        dispreg_k<<<g(NB * H * W), blk, 0, stream>>>(CO, dsm, NB * H * W, D, H * W, -2.f, 8.f);
        upsample_add_k<<<g(NPIX), blk, 0, stream>>>(dsm, H, W, pred0, pred1, nullptr);
    }

    // ---------------- stage 2 ----------------
    {
        const int D = 5, H = 128, W = 320, DZ = 7, HZ = 130, WZ = 328;
        const size_t pcn = (size_t)NB * 4 * DZ * HZ * WZ;    // 9,551,360
        const size_t cpn = (size_t)NB * DZ * HZ * WZ;        // 2,387,840
        hipMemsetAsync(P,  0, pcn * 4, stream);
        hipMemsetAsync(Q,  0, pcn * 4, stream);
        hipMemsetAsync(CP, 0, cpn * 4, stream);
        const int total = NB * D * H * W;                    // 1,638,400
        wflow_k<<<g(NB * H * W), blk, 0, stream>>>(pred1, wfl, H, W, 4, 0.25f);
        costresp_k<<<g(total), blk, 0, stream>>>(f_l2, f_r2, wfl, CP, H, W, HZ, WZ);
        int ns8 = total / 8;                                 // 204,800
        convp_k<1, 4, 8, true, true><<<g(ns8), blk, 0, stream>>>(CP, w_in2, P, D, H, W, DZ, HZ, WZ, ns8);
        const float* src = P; float* dst = Q;
        for (int k = 0; k < 4; ++k) {
            convp_k<4, 4, 8, true, true><<<g(ns8), blk, 0, stream>>>(src, w_mid2 + k * 4 * 4 * 27, dst, D, H, W, DZ, HZ, WZ, ns8);
            const float* nsrc = dst; dst = (float*)src; src = nsrc;
        }
        convp_k<4, 1, 8, false, false><<<g(ns8), blk, 0, stream>>>(src, w_out2, CO, D, H, W, DZ, HZ, WZ, ns8);
        dispreg_k<<<g(NB * H * W), blk, 0, stream>>>(CO, dsm, NB * H * W, D, H * W, -2.f, 4.f);
        upsample_add_k<<<g(NPIX), blk, 0, stream>>>(dsm, H, W, pred1, pred2, nullptr);
    }
}

// Round 5
// 1053.718 us; speedup vs baseline: 1.4551x; 1.0086x over previous
//
#include <hip/hip_runtime.h>
#include <math.h>

// AnyNet stereo forward, fp32. Round 5: weights via scalar pipe (s_load from
// globally transposed [CI][27][CO] layout, wave-uniform indices) -- no LDS,
// no broadcast ds_reads. Padded activations from R4 kept (branch-free taps).

#define FULL_H 512
#define FULL_W 1280
#define NB 8
#define NPIX (NB * FULL_H * FULL_W)   // 5,242,880

// ---------------- weight transpose prep: [CO][CI][27] -> [CI][27][CO] ----------------
__device__ inline void wtr(const float* __restrict__ s, float* __restrict__ d,
                           int CO, int CI, int i) {
    int ci = i / (27 * CO);
    int r  = i - ci * 27 * CO;
    int tap = r / CO;
    int co  = r - tap * CO;
    d[i] = s[(co * CI + ci) * 27 + tap];
}

__global__ __launch_bounds__(256) void wprep_k(const float* __restrict__ in0,
                                               const float* __restrict__ mid0,
                                               const float* __restrict__ out0,
                                               const float* __restrict__ in1,
                                               const float* __restrict__ mid1,
                                               const float* __restrict__ out1,
                                               const float* __restrict__ in2,
                                               const float* __restrict__ mid2,
                                               const float* __restrict__ out2,
                                               float* __restrict__ dst) {
    int i = blockIdx.x * 256 + threadIdx.x;
    if (i >= 32400) return;
    if (i < 432) {                    // in0: CO=16 CI=1
        wtr(in0, dst + 0, 16, 1, i - 0);
    } else if (i < 28080) {           // mid0 x4: CO=16 CI=16 (6912 each)
        int l = i - 432; int k = l / 6912; int li = l - k * 6912;
        wtr(mid0 + k * 6912, dst + 432 + k * 6912, 16, 16, li);
    } else if (i < 28512) {           // out0: CO=1 CI=16
        wtr(out0, dst + 28080, 1, 16, i - 28080);
    } else if (i < 28620) {           // in1: CO=4 CI=1
        wtr(in1, dst + 28512, 4, 1, i - 28512);
    } else if (i < 30348) {           // mid1 x4: CO=4 CI=4 (432 each)
        int l = i - 28620; int k = l / 432; int li = l - k * 432;
        wtr(mid1 + k * 432, dst + 28620 + k * 432, 4, 4, li);
    } else if (i < 30456) {           // out1: CO=1 CI=4
        wtr(out1, dst + 30348, 1, 4, i - 30348);
    } else if (i < 30564) {           // in2
        wtr(in2, dst + 30456, 4, 1, i - 30456);
    } else if (i < 32292) {           // mid2 x4
        int l = i - 30564; int k = l / 432; int li = l - k * 432;
        wtr(mid2 + k * 432, dst + 30564 + k * 432, 4, 4, li);
    } else {                          // out2
        wtr(out2, dst + 32292, 1, 4, i - 32292);
    }
}

// ---------------- stage-0 L1 cost volume -> padded ----------------
__global__ __launch_bounds__(256) void cost0p_k(const float* __restrict__ fl,
                                                const float* __restrict__ fr,
                                                float* __restrict__ costp) {
    const int H = 32, W = 80, D = 12, C = 8;
    const int DZ = 14, HZ = 34, WZ = 88;
    int idx = blockIdx.x * 256 + threadIdx.x;
    int total = NB * D * H * W;
    if (idx >= total) return;
    int w = idx % W; int t = idx / W;
    int h = t % H; t /= H;
    int d = t % D; int b = t / D;
    int src = w - d;
    float acc = 0.f;
    for (int c = 0; c < C; ++c) {
        int base = ((b * C + c) * H + h) * W;
        float flv = fl[base + w];
        float frv = (src >= 0) ? fr[base + src] : 0.f;
        acc += fabsf(flv - frv);
    }
    costp[((b * DZ + (d + 1)) * HZ + (h + 1)) * WZ + (w + 4)] = acc;
}

// ---------------- residual (warped) cost volume -> padded ----------------
__global__ __launch_bounds__(256) void costresp_k(const float* __restrict__ fl,
                                                  const float* __restrict__ fr,
                                                  const float* __restrict__ wf,
                                                  float* __restrict__ costp,
                                                  int H, int W, int HZ, int WZ) {
    const int C = 8, S = 5, DZ = 7;
    int idx = blockIdx.x * 256 + threadIdx.x;
    int total = NB * S * H * W;
    if (idx >= total) return;
    int w = idx % W; int t = idx / W;
    int h = t % H; t /= H;
    int s = t % S; int b = t / S;
    float disp  = wf[(b * H + h) * W + w];
    float shift = (float)(s - 2);
    float xs  = (float)w - (disp - shift);
    float x0f = floorf(xs);
    float w1  = xs - x0f;
    float x0fc = fminf(fmaxf(x0f, -2.f), (float)W);
    int x0 = (int)x0fc;
    int x1 = x0 + 1;
    float m0 = (x0 >= 0 && x0 <= W - 1) ? (1.f - w1) : 0.f;
    float m1 = (x1 >= 0 && x1 <= W - 1) ? w1 : 0.f;
    int x0c = min(max(x0, 0), W - 1);
    int x1c = min(max(x1, 0), W - 1);
    float acc = 0.f;
    const float* flb = fl + ((b * C) * H + h) * W;
    const float* frb = fr + ((b * C) * H + h) * W;
    for (int c = 0; c < C; ++c) {
        float v = frb[x0c] * m0 + frb[x1c] * m1;
        acc += fabsf(flb[w] - v);
        flb += H * W;
        frb += H * W;
    }
    costp[((b * DZ + (s + 1)) * HZ + (h + 1)) * WZ + (w + 4)] = acc;
}

// ---------------- padded branch-free 3x3x3 SAME conv3d, scalar-pipe weights ----------------
// x: padded [B,CIN,DZ,HZ,WZ]; wt: transposed [CIN][27][COUT] (wave-uniform reads
// -> s_load through constant cache; v_fma takes SGPR operand);
// y: padded [B,COUT,DZ,HZ,WZ] (PADOUT) or unpadded [B,COUT,D,H,W].
template <int CIN, int COUT, int WT, bool RELU, bool PADOUT>
__global__ __launch_bounds__(256) void convp_k(const float* __restrict__ x,
                                               const float* __restrict__ wt,
                                               float* __restrict__ y,
                                               int D, int H, int W,
                                               int DZ, int HZ, int WZ,
                                               int nstrips) {
    int idx = blockIdx.x * 256 + threadIdx.x;
    if (idx >= nstrips) return;
    const int SW = W / WT;
    int sw = idx % SW; int t = idx / SW;
    int h = t % H; t /= H;
    int d = t % D; int b = t / D;
    const int wcol = sw * WT + 4;
    const int zhs = HZ * WZ;
    const int zcs = DZ * zhs;

    float acc[COUT][WT];
#pragma unroll
    for (int co = 0; co < COUT; ++co)
#pragma unroll
        for (int wt_ = 0; wt_ < WT; ++wt_) acc[co][wt_] = 0.f;

    const float* xb = x + (size_t)b * CIN * zcs + (size_t)d * zhs + (size_t)h * WZ + wcol;

    for (int ci = 0; ci < CIN; ++ci) {
        const float* xc = xb + (size_t)ci * zcs;
#pragma unroll
        for (int kd = 0; kd < 3; ++kd) {
#pragma unroll
            for (int kh = 0; kh < 3; ++kh) {
                const float* row = xc + kd * zhs + kh * WZ;
                float xr[WT + 2];
#pragma unroll
                for (int j = 0; j < WT / 4; ++j) {
                    float4 v = *reinterpret_cast<const float4*>(row + j * 4);
                    xr[1 + j * 4 + 0] = v.x; xr[1 + j * 4 + 1] = v.y;
                    xr[1 + j * 4 + 2] = v.z; xr[1 + j * 4 + 3] = v.w;
                }
                xr[0]      = row[-1];
                xr[WT + 1] = row[WT];
                const int tapbase = ci * 27 + kd * 9 + kh * 3;
#pragma unroll
                for (int kw = 0; kw < 3; ++kw) {
                    // wave-uniform weight reads (scalar pipe)
                    const float* wp = wt + (tapbase + kw) * COUT;
#pragma unroll
                    for (int co = 0; co < COUT; ++co) {
                        float wv = wp[co];
#pragma unroll
                        for (int wt_ = 0; wt_ < WT; ++wt_)
                            acc[co][wt_] = fmaf(xr[wt_ + kw], wv, acc[co][wt_]);
                    }
                }
            }
        }
    }

    if constexpr (PADOUT) {
        float* yb = y + (size_t)b * COUT * zcs + (size_t)(d + 1) * zhs + (size_t)(h + 1) * WZ + wcol;
#pragma unroll
        for (int co = 0; co < COUT; ++co) {
#pragma unroll
            for (int j = 0; j < WT / 4; ++j) {
                float4 v;
                v.x = acc[co][j * 4 + 0]; v.y = acc[co][j * 4 + 1];
                v.z = acc[co][j * 4 + 2]; v.w = acc[co][j * 4 + 3];
                if (RELU) {
                    v.x = fmaxf(v.x, 0.f); v.y = fmaxf(v.y, 0.f);
                    v.z = fmaxf(v.z, 0.f); v.w = fmaxf(v.w, 0.f);
                }
                *reinterpret_cast<float4*>(yb + (size_t)co * zcs + j * 4) = v;
            }
        }
    } else {
        const int chs = D * H * W;
        float* yb = y + (size_t)b * COUT * chs + (d * H + h) * W + sw * WT;
#pragma unroll
        for (int co = 0; co < COUT; ++co) {
#pragma unroll
            for (int j = 0; j < WT / 4; ++j) {
                float4 v;
                v.x = acc[co][j * 4 + 0]; v.y = acc[co][j * 4 + 1];
                v.z = acc[co][j * 4 + 2]; v.w = acc[co][j * 4 + 3];
                if (RELU) {
                    v.x = fmaxf(v.x, 0.f); v.y = fmaxf(v.y, 0.f);
                    v.z = fmaxf(v.z, 0.f); v.w = fmaxf(v.w, 0.f);
                }
                *reinterpret_cast<float4*>(yb + (size_t)co * chs + j * 4) = v;
            }
        }
    }
}

// ---------------- softargmin disparity regression ----------------
__global__ __launch_bounds__(256) void dispreg_k(const float* __restrict__ cost,
                                                 float* __restrict__ dsm,
                                                 int total, int D, int HW,
                                                 float dstart, float scale) {
    int idx = blockIdx.x * 256 + threadIdx.x;
    if (idx >= total) return;
    int hw = idx % HW; int b = idx / HW;
    const float* c = cost + b * D * HW + hw;
    float m = -1e30f;
    for (int d = 0; d < D; ++d) m = fmaxf(m, -c[d * HW]);
    float s = 0.f, ws = 0.f;
    for (int d = 0; d < D; ++d) {
        float e = expf(-c[d * HW] - m);
        s += e;
        ws = fmaf(e, dstart + (float)d, ws);
    }
    dsm[idx] = ws / s * scale;
}

// ---------------- bilinear upsample + optional residual + optional depth ----------------
__global__ __launch_bounds__(256) void upsample_add_k(const float* __restrict__ s,
                                                      int sh, int sw,
                                                      const float* __restrict__ prev,
                                                      float* __restrict__ out,
                                                      float* __restrict__ dep) {
    int idx = blockIdx.x * 256 + threadIdx.x;
    if (idx >= NPIX) return;
    int x = idx % FULL_W; int t = idx / FULL_W;
    int y = t % FULL_H; int b = t / FULL_H;
    float fy = (y + 0.5f) * ((float)sh / FULL_H) - 0.5f;
    float fx = (x + 0.5f) * ((float)sw / FULL_W) - 0.5f;
    int y0 = (int)floorf(fy); float wy = fy - (float)y0;
    int x0 = (int)floorf(fx); float wx = fx - (float)x0;
    int y0c = min(max(y0, 0), sh - 1), y1c = min(max(y0 + 1, 0), sh - 1);
    int x0c = min(max(x0, 0), sw - 1), x1c = min(max(x0 + 1, 0), sw - 1);
    const float* sb = s + b * sh * sw;
    float v00 = sb[y0c * sw + x0c], v01 = sb[y0c * sw + x1c];
    float v10 = sb[y1c * sw + x0c], v11 = sb[y1c * sw + x1c];
    float v = (1.f - wy) * ((1.f - wx) * v00 + wx * v01) +
              wy        * ((1.f - wx) * v10 + wx * v11);
    if (prev) v += prev[idx];
    out[idx] = v;
    if (dep) {
        float p = fabsf(v);
        float d = 64.f / p;                 // BASELINE*FOCAL
        if (isnan(d)) d = 100.f;
        d = fminf(fmaxf(d, 0.1f), 100.f);
        dep[idx] = d;
    }
}

// ---------------- antialiased triangle downsample + scale ----------------
__global__ __launch_bounds__(256) void wflow_k(const float* __restrict__ pred,
                                               float* __restrict__ wf,
                                               int oh, int ow, int f, float scale) {
    int idx = blockIdx.x * 256 + threadIdx.x;
    int total = NB * oh * ow;
    if (idx >= total) return;
    int ox = idx % ow; int t = idx / ow;
    int oy = t % oh; int b = t / oh;
    float ff = (float)f, invf = 1.f / (float)f;
    float cy = (oy + 0.5f) * ff - 0.5f;
    float cx = (ox + 0.5f) * ff - 0.5f;
    int ylo = max((int)ceilf(cy - ff), 0);
    int yhi = min((int)floorf(cy + ff), FULL_H - 1);
    int xlo = max((int)ceilf(cx - ff), 0);
    int xhi = min((int)floorf(cx + ff), FULL_W - 1);
    const float* pb = pred + b * FULL_H * FULL_W;
    float acc = 0.f, wys = 0.f, wxs = 0.f;
    for (int iy = ylo; iy <= yhi; ++iy) {
        float wy = 1.f - fabsf((float)iy - cy) * invf;
        wys += wy;
        float rowacc = 0.f;
        const float* row = pb + iy * FULL_W;
        for (int ix = xlo; ix <= xhi; ++ix) {
            float wx = 1.f - fabsf((float)ix - cx) * invf;
            rowacc = fmaf(wx, row[ix], rowacc);
        }
        acc = fmaf(wy, rowacc, acc);
    }
    for (int ix = xlo; ix <= xhi; ++ix) wxs += 1.f - fabsf((float)ix - cx) * invf;
    wf[idx] = acc / (wys * wxs) * scale;
}

static inline dim3 g(int n) { return dim3((n + 255) / 256); }

extern "C" void kernel_launch(void* const* d_in, const int* in_sizes, int n_in,
                              void* d_out, int out_size, void* d_ws, size_t ws_size,
                              hipStream_t stream) {
    const float* f_l0  = (const float*)d_in[0];
    const float* f_r0  = (const float*)d_in[1];
    const float* f_l1  = (const float*)d_in[2];
    const float* f_r1  = (const float*)d_in[3];
    const float* f_l2  = (const float*)d_in[4];
    const float* f_r2  = (const float*)d_in[5];
    const float* w_in0  = (const float*)d_in[6];
    const float* w_mid0 = (const float*)d_in[7];
    const float* w_out0 = (const float*)d_in[8];
    const float* w_in1  = (const float*)d_in[9];
    const float* w_mid1 = (const float*)d_in[10];
    const float* w_out1 = (const float*)d_in[11];
    const float* w_in2  = (const float*)d_in[12];
    const float* w_mid2 = (const float*)d_in[13];
    const float* w_out2 = (const float*)d_in[14];

    float* out   = (float*)d_out;
    float* pred0 = out;
    float* pred1 = out + NPIX;
    float* pred2 = out + 2 * NPIX;
    float* depth = out + 3 * NPIX;

    // Workspace (floats):
    float* ws = (float*)d_ws;
    float* P    = ws;               // padded ping (max 9,551,360)
    float* Q    = ws + 9551360;     // padded pong
    float* CP   = ws + 19102720;    // padded cost input (max 2,387,840)
    float* CO   = ws + 21490560;    // unpadded conv output (max 1,638,400)
    float* dsm  = ws + 23128960;    // 327,680
    float* wfl  = ws + 23456640;    // 327,680
    float* WTR  = ws + 23784320;    // 32,400 transposed weights (end ~95.3 MB)

    // transposed weight offsets
    float* t_in0  = WTR + 0;
    float* t_mid0 = WTR + 432;      // 4 x 6912
    float* t_out0 = WTR + 28080;
    float* t_in1  = WTR + 28512;
    float* t_mid1 = WTR + 28620;    // 4 x 432
    float* t_out1 = WTR + 30348;
    float* t_in2  = WTR + 30456;
    float* t_mid2 = WTR + 30564;    // 4 x 432
    float* t_out2 = WTR + 32292;

    dim3 blk(256);

    wprep_k<<<g(32400), blk, 0, stream>>>(w_in0, w_mid0, w_out0, w_in1, w_mid1,
                                          w_out1, w_in2, w_mid2, w_out2, WTR);

    // ---------------- stage 0 ----------------
    {
        const int D = 12, H = 32, W = 80, DZ = 14, HZ = 34, WZ = 88;
        const size_t pcn = (size_t)NB * 16 * DZ * HZ * WZ;   // 5,361,664
        const size_t cpn = (size_t)NB * DZ * HZ * WZ;        //   335,104
        hipMemsetAsync(P,  0, pcn * 4, stream);
        hipMemsetAsync(Q,  0, pcn * 4, stream);
        hipMemsetAsync(CP, 0, cpn * 4, stream);
        const int total = NB * D * H * W;                    // 245,760
        cost0p_k<<<g(total), blk, 0, stream>>>(f_l0, f_r0, CP);
        int ns4 = total / 4;                                 // 61,440
        int ns8 = total / 8;                                 // 30,720
        convp_k<1, 16, 4, true, true><<<g(ns4), blk, 0, stream>>>(CP, t_in0, P, D, H, W, DZ, HZ, WZ, ns4);
        const float* src = P; float* dst = Q;
        for (int k = 0; k < 4; ++k) {
            convp_k<16, 16, 4, true, true><<<g(ns4), blk, 0, stream>>>(src, t_mid0 + k * 6912, dst, D, H, W, DZ, HZ, WZ, ns4);
            const float* nsrc = dst; dst = (float*)src; src = nsrc;
        }
        convp_k<16, 1, 8, false, false><<<g(ns8), blk, 0, stream>>>(src, t_out0, CO, D, H, W, DZ, HZ, WZ, ns8);
        dispreg_k<<<g(NB * H * W), blk, 0, stream>>>(CO, dsm, NB * H * W, D, H * W, 0.f, 16.f);
        upsample_add_k<<<g(NPIX), blk, 0, stream>>>(dsm, H, W, nullptr, pred0, depth);
    }

    // ---------------- stage 1 ----------------
    {
        const int D = 5, H = 64, W = 160, DZ = 7, HZ = 66, WZ = 168;
        const size_t pcn = (size_t)NB * 4 * DZ * HZ * WZ;    // 2,483,712
        const size_t cpn = (size_t)NB * DZ * HZ * WZ;        //   620,928
        hipMemsetAsync(P,  0, pcn * 4, stream);
        hipMemsetAsync(Q,  0, pcn * 4, stream);
        hipMemsetAsync(CP, 0, cpn * 4, stream);
        const int total = NB * D * H * W;                    // 409,600
        wflow_k<<<g(NB * H * W), blk, 0, stream>>>(pred0, wfl, H, W, 8, 0.125f);
        costresp_k<<<g(total), blk, 0, stream>>>(f_l1, f_r1, wfl, CP, H, W, HZ, WZ);
        int ns4 = total / 4;                                 // 102,400
        int ns8 = total / 8;                                 //  51,200
        convp_k<1, 4, 4, true, true><<<g(ns4), blk, 0, stream>>>(CP, t_in1, P, D, H, W, DZ, HZ, WZ, ns4);
        const float* src = P; float* dst = Q;
        for (int k = 0; k < 4; ++k) {
            convp_k<4, 4, 4, true, true><<<g(ns4), blk, 0, stream>>>(src, t_mid1 + k * 432, dst, D, H, W, DZ, HZ, WZ, ns4);
            const float* nsrc = dst; dst = (float*)src; src = nsrc;
        }
        convp_k<4, 1, 8, false, false><<<g(ns8), blk, 0, stream>>>(src, t_out1, CO, D, H, W, DZ, HZ, WZ, ns8);
        dispreg_k<<<g(NB * H * W), blk, 0, stream>>>(CO, dsm, NB * H * W, D, H * W, -2.f, 8.f);
        upsample_add_k<<<g(NPIX), blk, 0, stream>>>(dsm, H, W, pred0, pred1, nullptr);
    }

    // ---------------- stage 2 ----------------
    {
        const int D = 5, H = 128, W = 320, DZ = 7, HZ = 130, WZ = 328;
        const size_t pcn = (size_t)NB * 4 * DZ * HZ * WZ;    // 9,551,360
        const size_t cpn = (size_t)NB * DZ * HZ * WZ;        // 2,387,840
        hipMemsetAsync(P,  0, pcn * 4, stream);
        hipMemsetAsync(Q,  0, pcn * 4, stream);
        hipMemsetAsync(CP, 0, cpn * 4, stream);
        const int total = NB * D * H * W;                    // 1,638,400
        wflow_k<<<g(NB * H * W), blk, 0, stream>>>(pred1, wfl, H, W, 4, 0.25f);
        costresp_k<<<g(total), blk, 0, stream>>>(f_l2, f_r2, wfl, CP, H, W, HZ, WZ);
        int ns8 = total / 8;                                 // 204,800
        convp_k<1, 4, 8, true, true><<<g(ns8), blk, 0, stream>>>(CP, t_in2, P, D, H, W, DZ, HZ, WZ, ns8);
        const float* src = P; float* dst = Q;
        for (int k = 0; k < 4; ++k) {
            convp_k<4, 4, 8, true, true><<<g(ns8), blk, 0, stream>>>(src, t_mid2 + k * 432, dst, D, H, W, DZ, HZ, WZ, ns8);
            const float* nsrc = dst; dst = (float*)src; src = nsrc;
        }
        convp_k<4, 1, 8, false, false><<<g(ns8), blk, 0, stream>>>(src, t_out2, CO, D, H, W, DZ, HZ, WZ, ns8);
        dispreg_k<<<g(NB * H * W), blk, 0, stream>>>(CO, dsm, NB * H * W, D, H * W, -2.f, 4.f);
        upsample_add_k<<<g(NPIX), blk, 0, stream>>>(dsm, H, W, pred1, pred2, nullptr);
    }
}